// Round 14
// baseline (531.949 us; speedup 1.0000x reference)
//
#include <hip/hip_runtime.h>
#include <stdint.h>

#define HOR 128
#define NPATH 4096
#define BATCH 8
#define DM 512
#define H 64
#define BN (BATCH*NPATH)

typedef __attribute__((ext_vector_type(8))) short s16x8;   // 8 bf16 = 4 VGPRs
typedef __attribute__((ext_vector_type(4))) float f32x4;   // MFMA C/D

// ---------------- threefry2x32 (JAX-exact) ----------------
__device__ __forceinline__ uint32_t rotl32(uint32_t x, int r) {
  return (x << r) | (x >> (32 - r));
}

__device__ __forceinline__ void tf2x32(uint32_t k0, uint32_t k1,
                                       uint32_t& x0, uint32_t& x1) {
  uint32_t k2 = k0 ^ k1 ^ 0x1BD11BDAu;
  x0 += k0; x1 += k1;
#define TFR4(a,b,c,d) \
  x0 += x1; x1 = rotl32(x1,a); x1 ^= x0; \
  x0 += x1; x1 = rotl32(x1,b); x1 ^= x0; \
  x0 += x1; x1 = rotl32(x1,c); x1 ^= x0; \
  x0 += x1; x1 = rotl32(x1,d); x1 ^= x0;
  TFR4(13,15,26,6)  x0 += k1; x1 += k2 + 1u;
  TFR4(17,29,16,24) x0 += k2; x1 += k0 + 2u;
  TFR4(13,15,26,6)  x0 += k0; x1 += k1 + 3u;
  TFR4(17,29,16,24) x0 += k1; x1 += k2 + 4u;
  TFR4(13,15,26,6)  x0 += k2; x1 += k0 + 5u;
#undef TFR4
}

// ---------------- math helpers ----------------
__device__ __forceinline__ float rcpf(float x) { return __builtin_amdgcn_rcpf(x); }
__device__ __forceinline__ float siluf(float x) {
  return x * rcpf(1.0f + __expf(-x));
}
// paired silu: one v_rcp for two sigmoids (bit-identical to R12, which passed)
__device__ __forceinline__ void silu2(float x0, float x1, float& o0, float& o1) {
  const float e0 = __expf(-x0), e1 = __expf(-x1);
  const float d0 = 1.0f + e0,   d1 = 1.0f + e1;
  const float r  = rcpf(d0 * d1);
  o0 = x0 * (r * d1);
  o1 = x1 * (r * d0);
}
__device__ __forceinline__ float softplusf(float x) {     // k_pre only (unchanged)
  return fmaxf(x, 0.0f) + log1pf(__expf(-fabsf(x)));
}
// in-loop softplus: z = e^-|x| in (0,1] -> 1+z in (1,2], v_log ~1ulp there.
__device__ __forceinline__ float softplus_fast(float x) {
  return fmaxf(x, 0.0f) + __logf(1.0f + __expf(-fabsf(x)));
}

__device__ __forceinline__ float bits_to_normal(uint32_t bits) {
  uint32_t fb = (bits >> 9) | 0x3F800000u;
  float f = __uint_as_float(fb) - 1.0f;
  float u = fmaf(f, 2.0f, -0.99999994f);
  u = fmaxf(u, -0.99999994f);
  float w = -log1pf(-u * u);
  float p;
  if (w < 5.0f) {
    w = w - 2.5f;
    p = 2.81022636e-08f;
    p = fmaf(p, w, 3.43273939e-07f);
    p = fmaf(p, w, -3.5233877e-06f);
    p = fmaf(p, w, -4.39150654e-06f);
    p = fmaf(p, w, 0.00021858087f);
    p = fmaf(p, w, -0.00125372503f);
    p = fmaf(p, w, -0.00417768164f);
    p = fmaf(p, w, 0.246640727f);
    p = fmaf(p, w, 1.50140941f);
  } else {
    w = sqrtf(w) - 3.0f;
    p = -0.000200214257f;
    p = fmaf(p, w, 0.000100950558f);
    p = fmaf(p, w, 0.00134934322f);
    p = fmaf(p, w, -0.00367342844f);
    p = fmaf(p, w, 0.00573950773f);
    p = fmaf(p, w, -0.0076224613f);
    p = fmaf(p, w, 0.00943887047f);
    p = fmaf(p, w, 1.00167406f);
    p = fmaf(p, w, 2.83297682f);
  }
  return 1.41421356237f * (p * u);
}

// pack top-16 bits of two fp32 -> one dword of 2 bf16 (truncation round)
__device__ __forceinline__ uint32_t pack_hi16(uint32_t hi_src, uint32_t lo_src) {
  return __builtin_amdgcn_perm(hi_src, lo_src, 0x07060302u);
}

union FragU { uint32_t u[4]; s16x8 v; };

// split 8 fp32 -> 3 bf16x8 fragments: x = hi + mid + lo + O(2^-24 |x|)
__device__ __forceinline__ void split3(const float (&x)[8],
                                       s16x8& fh, s16x8& fm, s16x8& fl) {
  FragU Hh, Mm, Ll;
  #pragma unroll
  for (int d = 0; d < 4; ++d) {
    float x0 = x[2*d], x1 = x[2*d+1];
    uint32_t a0 = __float_as_uint(x0), a1 = __float_as_uint(x1);
    float r10 = x0 - __uint_as_float(a0 & 0xFFFF0000u);
    float r11 = x1 - __uint_as_float(a1 & 0xFFFF0000u);
    uint32_t m0 = __float_as_uint(r10), m1 = __float_as_uint(r11);
    float r20 = r10 - __uint_as_float(m0 & 0xFFFF0000u);
    float r21 = r11 - __uint_as_float(m1 & 0xFFFF0000u);
    Hh.u[d] = pack_hi16(a1, a0);
    Mm.u[d] = pack_hi16(m1, m0);
    Ll.u[d] = pack_hi16(__float_as_uint(r21), __float_as_uint(r20));
  }
  fh = Hh.v; fm = Mm.v; fl = Ll.v;
}

#define MFMA16(A, B, C) __builtin_amdgcn_mfma_f32_16x16x32_bf16((A), (B), (C), 0, 0, 0)

// ws layout (floats): [0,512) base_f1[b][j], [512,1024) base_g1[b][j],
// (u32 view) [1024,1152) keyA[t], [1152,1280) keyB[t]

__global__ void k_pre(const float* __restrict__ h_t,
                      const float* __restrict__ W_f1, const float* __restrict__ b_f1,
                      const float* __restrict__ W_g1, const float* __restrict__ b_g1,
                      const float* __restrict__ W_mu, const float* __restrict__ b_mu,
                      const float* __restrict__ W_sig, const float* __restrict__ b_sig,
                      float* __restrict__ out, float* __restrict__ ws) {
  int j = threadIdx.x;           // 0..63
  int b = blockIdx.x;
  if (b == 8) {
    uint32_t* keyA = (uint32_t*)ws + 1024;
    uint32_t* keyB = (uint32_t*)ws + 1152;
    for (int t = j; t < HOR; t += 64) {
      uint32_t x0 = 0u, x1 = (uint32_t)t;
      tf2x32(0u, 42u, x0, x1);
      keyA[t] = x0; keyB[t] = x1;
    }
    return;
  }
  const float* h = h_t + b * DM;
  float accF = b_f1[j], accG = b_g1[j];
  float pm = 0.0f, ps = 0.0f;
  #pragma unroll 4
  for (int d = 0; d < DM; ++d) {
    float hv = h[d];
    accF = fmaf(hv, W_f1[d * H + j], accF);
    accG = fmaf(hv, W_g1[d * H + j], accG);
  }
  ws[b * H + j] = accF;
  ws[512 + b * H + j] = accG;
  for (int d = j; d < DM; d += 64) {
    pm = fmaf(h[d], W_mu[d], pm);
    ps = fmaf(h[d], W_sig[d], ps);
  }
  #pragma unroll
  for (int off = 32; off > 0; off >>= 1) {
    pm += __shfl_down(pm, off);
    ps += __shfl_down(ps, off);
  }
  if (j == 0) {
    out[BN * HOR + b] = pm + b_mu[0];
    out[BN * HOR + 8 + b] = softplusf(ps + b_sig[0]) + 1e-6f;
  }
}

// -----------------------------------------------------------------------------
// R14 = R13 resubmitted (R13 bench was an infra failure, not a kernel verdict).
// R13 = R12 numerics, 2-ROW-GROUP ILP restructure.
//   Evidence: R10 (serial-tail cut) -36us, R11/R12 (instr-count cuts) ~0
//   => latency-bound at 2 waves/SIMD (grid-capped); pipe-work audit says only
//   ~45% of the 7855cy/SIMD-step wall is real work. Barrier-split waves were
//   measured bad (R5-R7). Remaining lever: ILP — each wave owns TWO 16-row
//   groups (32 rows/wave, 1024 waves = 1/SIMD). Groups share ALL weights
//   (aw, f1, g-net, f3: zero extra weight state; one set of LDS loads feeds
//   both) and duplicate only dynamic state (y, c[4], frags, reductions).
//   Two independent dep-chains interleave in one instruction stream.
//   launch_bounds(256,1): empirical law (256,2)->128-reg target,
//   (256,4)->64 => (256,1)->256-reg target; live set ~230 fits.
//   Per-row math bit-identical to R12 (passed).
// -----------------------------------------------------------------------------
__global__ __launch_bounds__(256, 1)
void k_sde(const float* __restrict__ ip,
           const float* __restrict__ W_f1, const float* __restrict__ W_f2,
           const float* __restrict__ b_f2, const float* __restrict__ W_f3,
           const float* __restrict__ b_f3, const float* __restrict__ W_g1,
           const float* __restrict__ W_g2, const float* __restrict__ b_g2,
           float* __restrict__ out, const float* __restrict__ ws) {
  __shared__ __align__(16) float sW2[H * H];          // prologue staging only
  __shared__ __align__(16) float sF1y[H], sF1t[H], sBF[H];
  __shared__ __align__(16) float sGy[H], sGt[H], sBG[H], sG2[H];
  __shared__ __align__(16) float sF3[H], sBf2[H];
  __shared__ uint32_t sKA[HOR], sKB[HOR];

  const int tid  = threadIdx.x;
  const int rblk = blockIdx.x * 128;      // 128 rows per block (4 waves x 32)
  const int b    = rblk >> 12;            // batch: uniform per block (4096|128)

  #pragma unroll
  for (int m = 0; m < 16; ++m) sW2[tid + 256 * m] = W_f2[tid + 256 * m];
  if (tid < 64) {
    sF1y[tid] = W_f1[512 * H + tid];
    sF1t[tid] = W_f1[513 * H + tid];
    sGy[tid]  = W_g1[512 * H + tid];
    sGt[tid]  = W_g1[513 * H + tid];
    sF3[tid]  = W_f3[tid];
    sG2[tid]  = W_g2[tid];
    sBf2[tid] = b_f2[tid];
  } else if (tid < 128) {
    int i = tid - 64;
    sBF[i] = ws[b * H + i];
    sBG[i] = ws[512 + b * H + i];
  } else {
    const uint32_t* kws = (const uint32_t*)ws;
    int t = tid - 128;
    sKA[t] = kws[1024 + t];
    sKB[t] = kws[1152 + t];
  }
  __syncthreads();

  const int l  = tid & 63;
  const int wv = tid >> 6;
  const int rl = l & 15;                  // row-local / D column / B column
  const int h  = l >> 4;                  // k-group quarter
  const int rA = rblk + wv * 32 + rl;     // group-A global row
  const int rB = rA + 16;                 // group-B global row

  // ---- static A fragments: W2^T, 3-way bf16 split (96 VGPRs, SHARED) ----
  s16x8 aw[4][2][3];
  #pragma unroll
  for (int mt = 0; mt < 4; ++mt) {
    #pragma unroll
    for (int s = 0; s < 2; ++s) {
      float xv[8];
      #pragma unroll
      for (int e = 0; e < 8; ++e)
        xv[e] = sW2[(32 * s + 8 * h + e) * H + 16 * mt + rl];
      split3(xv, aw[mt][s][0], aw[mt][s][1], aw[mt][s][2]);
    }
  }

  // per-lane f3 / b_f2 along D rows j = 16*mt + 4*h + reg (SHARED)
  f32x4 f3v[4], bf2v[4];
  #pragma unroll
  for (int mt = 0; mt < 4; ++mt) {
    f3v[mt]  = *(const f32x4*)&sF3[16 * mt + 4 * h];
    bf2v[mt] = *(const f32x4*)&sBf2[16 * mt + 4 * h];
  }

  // hoisted f1-row weights at this lane's k slots (48 VGPRs, SHARED)
  f32x4 wy[2][2], wt1[2][2], wb[2][2];
  #pragma unroll
  for (int s = 0; s < 2; ++s) {
    const int k0 = 32 * s + 8 * h;
    wy[s][0]  = *(const f32x4*)&sF1y[k0]; wy[s][1]  = *(const f32x4*)&sF1y[k0 + 4];
    wt1[s][0] = *(const f32x4*)&sF1t[k0]; wt1[s][1] = *(const f32x4*)&sF1t[k0 + 4];
    wb[s][0]  = *(const f32x4*)&sBF[k0];  wb[s][1]  = *(const f32x4*)&sBF[k0 + 4];
  }

  const float bf3 = b_f3[0];
  const float bg2 = b_g2[0];
  float yA = logf(ip[b]);
  float yB = yA;
  float zzA = 0.0f, zzB = 0.0f;
  float sbA0 = 0.f, sbA1 = 0.f, sbA2 = 0.f, sbA3 = 0.f;
  float sbB0 = 0.f, sbB1 = 0.f, sbB2 = 0.f, sbB3 = 0.f;

  #pragma unroll 1
  for (int t = 0; t < HOR; ++t) {
    // one threefry per lane per group per 4 steps
    if ((t & 3) == 0) {
      const int tk = t + h;
      uint32_t x0 = 0u, x1 = (uint32_t)rA;
      tf2x32(sKA[tk], sKB[tk], x0, x1);
      zzA = bits_to_normal(x0 ^ x1);
      uint32_t y0 = 0u, y1 = (uint32_t)rB;
      tf2x32(sKA[tk], sKB[tk], y0, y1);
      zzB = bits_to_normal(y0 ^ y1);
    }
    const float zA = __shfl(zzA, rl + 16 * (t & 3));
    const float zB = __shfl(zzB, rl + 16 * (t & 3));
    const float tt = (float)t;

    // C init = b_f2[j]
    f32x4 cA[4], cB[4];
    #pragma unroll
    for (int mt = 0; mt < 4; ++mt) { cA[mt] = bf2v[mt]; cB[mt] = bf2v[mt]; }

    // ---- B fragments for both groups, both s phases ----
    s16x8 bhA[2], bmA[2], blA[2], bhB[2], bmB[2], blB[2];
    #pragma unroll
    for (int s = 0; s < 2; ++s) {
      float pvA[8], pvB[8], hvA[8], hvB[8];
      #pragma unroll
      for (int d2 = 0; d2 < 2; ++d2) {
        const f32x4 a_ = wy[s][d2], b_ = wt1[s][d2], cc = wb[s][d2];
        const float tb0 = fmaf(tt, b_.x, cc.x);
        const float tb1 = fmaf(tt, b_.y, cc.y);
        const float tb2 = fmaf(tt, b_.z, cc.z);
        const float tb3 = fmaf(tt, b_.w, cc.w);
        pvA[4*d2+0] = fmaf(yA, a_.x, tb0);  pvB[4*d2+0] = fmaf(yB, a_.x, tb0);
        pvA[4*d2+1] = fmaf(yA, a_.y, tb1);  pvB[4*d2+1] = fmaf(yB, a_.y, tb1);
        pvA[4*d2+2] = fmaf(yA, a_.z, tb2);  pvB[4*d2+2] = fmaf(yB, a_.z, tb2);
        pvA[4*d2+3] = fmaf(yA, a_.w, tb3);  pvB[4*d2+3] = fmaf(yB, a_.w, tb3);
      }
      silu2(pvA[0], pvA[1], hvA[0], hvA[1]); silu2(pvB[0], pvB[1], hvB[0], hvB[1]);
      silu2(pvA[2], pvA[3], hvA[2], hvA[3]); silu2(pvB[2], pvB[3], hvB[2], hvB[3]);
      silu2(pvA[4], pvA[5], hvA[4], hvA[5]); silu2(pvB[4], pvB[5], hvB[4], hvB[5]);
      silu2(pvA[6], pvA[7], hvA[6], hvA[7]); silu2(pvB[6], pvB[7], hvB[6], hvB[7]);
      split3(hvA, bhA[s], bmA[s], blA[s]);
      split3(hvB, bhB[s], bmB[s], blB[s]);
    }

    // ---- 96 MFMAs, term-major, A/B interleaved: 8-way acc rotation ----
    #pragma unroll
    for (int s = 0; s < 2; ++s) {
      #pragma unroll
      for (int mt = 0; mt < 4; ++mt) { cA[mt] = MFMA16(aw[mt][s][0], bhA[s], cA[mt]);
                                       cB[mt] = MFMA16(aw[mt][s][0], bhB[s], cB[mt]); } // hh
      #pragma unroll
      for (int mt = 0; mt < 4; ++mt) { cA[mt] = MFMA16(aw[mt][s][0], bmA[s], cA[mt]);
                                       cB[mt] = MFMA16(aw[mt][s][0], bmB[s], cB[mt]); } // hm
      #pragma unroll
      for (int mt = 0; mt < 4; ++mt) { cA[mt] = MFMA16(aw[mt][s][1], bhA[s], cA[mt]);
                                       cB[mt] = MFMA16(aw[mt][s][1], bhB[s], cB[mt]); } // mh
      #pragma unroll
      for (int mt = 0; mt < 4; ++mt) { cA[mt] = MFMA16(aw[mt][s][1], bmA[s], cA[mt]);
                                       cB[mt] = MFMA16(aw[mt][s][1], bmB[s], cB[mt]); } // mm
      #pragma unroll
      for (int mt = 0; mt < 4; ++mt) { cA[mt] = MFMA16(aw[mt][s][0], blA[s], cA[mt]);
                                       cB[mt] = MFMA16(aw[mt][s][0], blB[s], cB[mt]); } // hl
      #pragma unroll
      for (int mt = 0; mt < 4; ++mt) { cA[mt] = MFMA16(aw[mt][s][2], bhA[s], cA[mt]);
                                       cB[mt] = MFMA16(aw[mt][s][2], bhB[s], cB[mt]); } // lh
    }

    // ---- g-net: ONE set of LDS loads feeds BOTH groups ----
    int kg = 8 * h;
    asm volatile("" : "+v"(kg));
    float gA0, gA1, gA2, gA3, gB0, gB1, gB2, gB3;
    {
      const int k0 = kg;
      const f32x4 gy0 = *(const f32x4*)&sGy[k0], gy1 = *(const f32x4*)&sGy[k0 + 4];
      const f32x4 gt0 = *(const f32x4*)&sGt[k0], gt1 = *(const f32x4*)&sGt[k0 + 4];
      const f32x4 gb0 = *(const f32x4*)&sBG[k0], gb1 = *(const f32x4*)&sBG[k0 + 4];
      const f32x4 g20 = *(const f32x4*)&sG2[k0], g21 = *(const f32x4*)&sG2[k0 + 4];
      const float t0 = fmaf(tt, gt0.x, gb0.x), t1 = fmaf(tt, gt0.y, gb0.y);
      const float t2 = fmaf(tt, gt0.z, gb0.z), t3 = fmaf(tt, gt0.w, gb0.w);
      const float t4 = fmaf(tt, gt1.x, gb1.x), t5 = fmaf(tt, gt1.y, gb1.y);
      const float t6 = fmaf(tt, gt1.z, gb1.z), t7 = fmaf(tt, gt1.w, gb1.w);
      float sA0,sA1,sA2,sA3,sA4,sA5,sA6,sA7, sB0,sB1,sB2,sB3,sB4,sB5,sB6,sB7;
      silu2(fmaf(yA, gy0.x, t0), fmaf(yA, gy0.y, t1), sA0, sA1);
      silu2(fmaf(yB, gy0.x, t0), fmaf(yB, gy0.y, t1), sB0, sB1);
      silu2(fmaf(yA, gy0.z, t2), fmaf(yA, gy0.w, t3), sA2, sA3);
      silu2(fmaf(yB, gy0.z, t2), fmaf(yB, gy0.w, t3), sB2, sB3);
      silu2(fmaf(yA, gy1.x, t4), fmaf(yA, gy1.y, t5), sA4, sA5);
      silu2(fmaf(yB, gy1.x, t4), fmaf(yB, gy1.y, t5), sB4, sB5);
      silu2(fmaf(yA, gy1.z, t6), fmaf(yA, gy1.w, t7), sA6, sA7);
      silu2(fmaf(yB, gy1.z, t6), fmaf(yB, gy1.w, t7), sB6, sB7);
      gA0 = sA0 * g20.x;  gA1 = sA1 * g20.y;  gA2 = sA2 * g20.z;  gA3 = sA3 * g20.w;
      gB0 = sB0 * g20.x;  gB1 = sB1 * g20.y;  gB2 = sB2 * g20.z;  gB3 = sB3 * g20.w;
      gA0 = fmaf(sA4, g21.x, gA0); gA1 = fmaf(sA5, g21.y, gA1);
      gA2 = fmaf(sA6, g21.z, gA2); gA3 = fmaf(sA7, g21.w, gA3);
      gB0 = fmaf(sB4, g21.x, gB0); gB1 = fmaf(sB5, g21.y, gB1);
      gB2 = fmaf(sB6, g21.z, gB2); gB3 = fmaf(sB7, g21.w, gB3);
    }
    {
      const int k0 = kg + 32;
      const f32x4 gy0 = *(const f32x4*)&sGy[k0], gy1 = *(const f32x4*)&sGy[k0 + 4];
      const f32x4 gt0 = *(const f32x4*)&sGt[k0], gt1 = *(const f32x4*)&sGt[k0 + 4];
      const f32x4 gb0 = *(const f32x4*)&sBG[k0], gb1 = *(const f32x4*)&sBG[k0 + 4];
      const f32x4 g20 = *(const f32x4*)&sG2[k0], g21 = *(const f32x4*)&sG2[k0 + 4];
      const float t0 = fmaf(tt, gt0.x, gb0.x), t1 = fmaf(tt, gt0.y, gb0.y);
      const float t2 = fmaf(tt, gt0.z, gb0.z), t3 = fmaf(tt, gt0.w, gb0.w);
      const float t4 = fmaf(tt, gt1.x, gb1.x), t5 = fmaf(tt, gt1.y, gb1.y);
      const float t6 = fmaf(tt, gt1.z, gb1.z), t7 = fmaf(tt, gt1.w, gb1.w);
      float sA0,sA1,sA2,sA3,sA4,sA5,sA6,sA7, sB0,sB1,sB2,sB3,sB4,sB5,sB6,sB7;
      silu2(fmaf(yA, gy0.x, t0), fmaf(yA, gy0.y, t1), sA0, sA1);
      silu2(fmaf(yB, gy0.x, t0), fmaf(yB, gy0.y, t1), sB0, sB1);
      silu2(fmaf(yA, gy0.z, t2), fmaf(yA, gy0.w, t3), sA2, sA3);
      silu2(fmaf(yB, gy0.z, t2), fmaf(yB, gy0.w, t3), sB2, sB3);
      silu2(fmaf(yA, gy1.x, t4), fmaf(yA, gy1.y, t5), sA4, sA5);
      silu2(fmaf(yB, gy1.x, t4), fmaf(yB, gy1.y, t5), sB4, sB5);
      silu2(fmaf(yA, gy1.z, t6), fmaf(yA, gy1.w, t7), sA6, sA7);
      silu2(fmaf(yB, gy1.z, t6), fmaf(yB, gy1.w, t7), sB6, sB7);
      gA0 = fmaf(sA0, g20.x, gA0); gA1 = fmaf(sA1, g20.y, gA1);
      gA2 = fmaf(sA2, g20.z, gA2); gA3 = fmaf(sA3, g20.w, gA3);
      gB0 = fmaf(sB0, g20.x, gB0); gB1 = fmaf(sB1, g20.y, gB1);
      gB2 = fmaf(sB2, g20.z, gB2); gB3 = fmaf(sB3, g20.w, gB3);
      gA0 = fmaf(sA4, g21.x, gA0); gA1 = fmaf(sA5, g21.y, gA1);
      gA2 = fmaf(sA6, g21.z, gA2); gA3 = fmaf(sA7, g21.w, gA3);
      gB0 = fmaf(sB4, g21.x, gB0); gB1 = fmaf(sB5, g21.y, gB1);
      gB2 = fmaf(sB6, g21.z, gB2); gB3 = fmaf(sB7, g21.w, gB3);
    }
    const float gaA = (gA0 + gA1) + (gA2 + gA3);
    const float gaB = (gB0 + gB1) + (gB2 + gB3);
    const float gaAx = __shfl_xor(gaA, 16), gaAy = __shfl_xor(gaA, 32), gaAz = __shfl_xor(gaA, 48);
    const float gaBx = __shfl_xor(gaB, 16), gaBy = __shfl_xor(gaB, 32), gaBz = __shfl_xor(gaB, 48);

    // ---- f-head for both groups (VALU runs under ga's DS latency) ----
    float sA[16], sB[16];
    silu2(cA[0].x, cA[0].y, sA[0],  sA[1]);  silu2(cB[0].x, cB[0].y, sB[0],  sB[1]);
    silu2(cA[0].z, cA[0].w, sA[2],  sA[3]);  silu2(cB[0].z, cB[0].w, sB[2],  sB[3]);
    silu2(cA[1].x, cA[1].y, sA[4],  sA[5]);  silu2(cB[1].x, cB[1].y, sB[4],  sB[5]);
    silu2(cA[1].z, cA[1].w, sA[6],  sA[7]);  silu2(cB[1].z, cB[1].w, sB[6],  sB[7]);
    silu2(cA[2].x, cA[2].y, sA[8],  sA[9]);  silu2(cB[2].x, cB[2].y, sB[8],  sB[9]);
    silu2(cA[2].z, cA[2].w, sA[10], sA[11]); silu2(cB[2].z, cB[2].w, sB[10], sB[11]);
    silu2(cA[3].x, cA[3].y, sA[12], sA[13]); silu2(cB[3].x, cB[3].y, sB[12], sB[13]);
    silu2(cA[3].z, cA[3].w, sA[14], sA[15]); silu2(cB[3].z, cB[3].w, sB[14], sB[15]);
    float fA0 = sA[0]  * f3v[0].x, fB0 = sB[0]  * f3v[0].x;
    float fA1 = sA[4]  * f3v[1].x, fB1 = sB[4]  * f3v[1].x;
    float fA2 = sA[8]  * f3v[2].x, fB2 = sB[8]  * f3v[2].x;
    float fA3 = sA[12] * f3v[3].x, fB3 = sB[12] * f3v[3].x;
    fA0 = fmaf(sA[1],  f3v[0].y, fA0); fB0 = fmaf(sB[1],  f3v[0].y, fB0);
    fA1 = fmaf(sA[5],  f3v[1].y, fA1); fB1 = fmaf(sB[5],  f3v[1].y, fB1);
    fA2 = fmaf(sA[9],  f3v[2].y, fA2); fB2 = fmaf(sB[9],  f3v[2].y, fB2);
    fA3 = fmaf(sA[13], f3v[3].y, fA3); fB3 = fmaf(sB[13], f3v[3].y, fB3);
    fA0 = fmaf(sA[2],  f3v[0].z, fA0); fB0 = fmaf(sB[2],  f3v[0].z, fB0);
    fA1 = fmaf(sA[6],  f3v[1].z, fA1); fB1 = fmaf(sB[6],  f3v[1].z, fB1);
    fA2 = fmaf(sA[10], f3v[2].z, fA2); fB2 = fmaf(sB[10], f3v[2].z, fB2);
    fA3 = fmaf(sA[14], f3v[3].z, fA3); fB3 = fmaf(sB[14], f3v[3].z, fB3);
    fA0 = fmaf(sA[3],  f3v[0].w, fA0); fB0 = fmaf(sB[3],  f3v[0].w, fB0);
    fA1 = fmaf(sA[7],  f3v[1].w, fA1); fB1 = fmaf(sB[7],  f3v[1].w, fB1);
    fA2 = fmaf(sA[11], f3v[2].w, fA2); fB2 = fmaf(sB[11], f3v[2].w, fB2);
    fA3 = fmaf(sA[15], f3v[3].w, fA3); fB3 = fmaf(sB[15], f3v[3].w, fB3);
    const float faA = (fA0 + fA1) + (fA2 + fA3);
    const float faB = (fB0 + fB1) + (fB2 + fB3);
    const float faAx = __shfl_xor(faA, 16), faAy = __shfl_xor(faA, 32), faAz = __shfl_xor(faA, 48);
    const float faBx = __shfl_xor(faB, 16), faBy = __shfl_xor(faB, 32), faBz = __shfl_xor(faB, 48);

    const float gaAT = (gaA + gaAx) + (gaAy + gaAz);
    const float gaBT = (gaB + gaBx) + (gaBy + gaBz);
    const float ggA  = softplus_fast(bg2 + gaAT) + 1e-6f;
    const float ggB  = softplus_fast(bg2 + gaBT) + 1e-6f;
    const float faAT = (faA + faAx) + (faAy + faAz);
    const float faBT = (faB + faBx) + (faBy + faBz);

    // Euler-Maruyama steps
    yA = (yA + (bf3 + faAT)) + ggA * zA;
    yB = (yB + (bf3 + faBT)) + ggB * zB;
    const float eA = __expf(fminf(fmaxf(yA, -20.0f), 20.0f));
    const float eB = __expf(fminf(fmaxf(yB, -20.0f), 20.0f));
    if (((t >> 2) & 3) == h) {
      sbA0 = sbA1; sbA1 = sbA2; sbA2 = sbA3; sbA3 = eA;
      sbB0 = sbB1; sbB1 = sbB2; sbB2 = sbB3; sbB3 = eB;
    }
    if ((t & 15) == 15) {
      f32x4 vA; vA.x = sbA0; vA.y = sbA1; vA.z = sbA2; vA.w = sbA3;
      f32x4 vB; vB.x = sbB0; vB.y = sbB1; vB.z = sbB2; vB.w = sbB3;
      *(f32x4*)&out[(size_t)rA * HOR + (t & ~15) + 4 * h] = vA;
      *(f32x4*)&out[(size_t)rB * HOR + (t & ~15) + 4 * h] = vB;
    }
  }
}

extern "C" void kernel_launch(void* const* d_in, const int* in_sizes, int n_in,
                              void* d_out, int out_size, void* d_ws, size_t ws_size,
                              hipStream_t stream) {
  const float* h_t   = (const float*)d_in[0];
  const float* ip    = (const float*)d_in[1];
  const float* W_f1  = (const float*)d_in[2];
  const float* b_f1  = (const float*)d_in[3];
  const float* W_f2  = (const float*)d_in[4];
  const float* b_f2  = (const float*)d_in[5];
  const float* W_f3  = (const float*)d_in[6];
  const float* b_f3  = (const float*)d_in[7];
  const float* W_g1  = (const float*)d_in[8];
  const float* b_g1  = (const float*)d_in[9];
  const float* W_g2  = (const float*)d_in[10];
  const float* b_g2  = (const float*)d_in[11];
  const float* W_mu  = (const float*)d_in[12];
  const float* b_mu  = (const float*)d_in[13];
  const float* W_sig = (const float*)d_in[14];
  const float* b_sig = (const float*)d_in[15];
  float* out = (float*)d_out;
  float* ws  = (float*)d_ws;

  hipLaunchKernelGGL(k_pre, dim3(9), dim3(64), 0, stream,
                     h_t, W_f1, b_f1, W_g1, b_g1, W_mu, b_mu, W_sig, b_sig, out, ws);
  hipLaunchKernelGGL(k_sde, dim3(BN / 128), dim3(256), 0, stream,
                     ip, W_f1, W_f2, b_f2, W_f3, b_f3, W_g1, W_g2, b_g2, out, ws);
}

// Round 16
// 458.023 us; speedup vs baseline: 1.1614x; 1.1614x over previous
//
#include <hip/hip_runtime.h>
#include <stdint.h>

#define HOR 128
#define NPATH 4096
#define BATCH 8
#define DM 512
#define H 64
#define BN (BATCH*NPATH)

typedef __attribute__((ext_vector_type(8))) short s16x8;       // raw 16-bit x8
typedef _Float16 h16x8 __attribute__((ext_vector_type(8)));    // 8 f16 = 4 VGPRs (MFMA operand)
typedef __fp16 fp16x2 __attribute__((ext_vector_type(2)));     // cvt_pkrtz return type
typedef __attribute__((ext_vector_type(4))) float f32x4;       // MFMA C/D

// ---------------- threefry2x32 (JAX-exact) ----------------
__device__ __forceinline__ uint32_t rotl32(uint32_t x, int r) {
  return (x << r) | (x >> (32 - r));
}

__device__ __forceinline__ void tf2x32(uint32_t k0, uint32_t k1,
                                       uint32_t& x0, uint32_t& x1) {
  uint32_t k2 = k0 ^ k1 ^ 0x1BD11BDAu;
  x0 += k0; x1 += k1;
#define TFR4(a,b,c,d) \
  x0 += x1; x1 = rotl32(x1,a); x1 ^= x0; \
  x0 += x1; x1 = rotl32(x1,b); x1 ^= x0; \
  x0 += x1; x1 = rotl32(x1,c); x1 ^= x0; \
  x0 += x1; x1 = rotl32(x1,d); x1 ^= x0;
  TFR4(13,15,26,6)  x0 += k1; x1 += k2 + 1u;
  TFR4(17,29,16,24) x0 += k2; x1 += k0 + 2u;
  TFR4(13,15,26,6)  x0 += k0; x1 += k1 + 3u;
  TFR4(17,29,16,24) x0 += k1; x1 += k2 + 4u;
  TFR4(13,15,26,6)  x0 += k2; x1 += k0 + 5u;
#undef TFR4
}

// ---------------- math helpers ----------------
__device__ __forceinline__ float rcpf(float x) { return __builtin_amdgcn_rcpf(x); }
__device__ __forceinline__ float siluf(float x) {
  return x * rcpf(1.0f + __expf(-x));
}
// paired silu: one v_rcp for two sigmoids (R12-verified)
__device__ __forceinline__ void silu2(float x0, float x1, float& o0, float& o1) {
  const float e0 = __expf(-x0), e1 = __expf(-x1);
  const float d0 = 1.0f + e0,   d1 = 1.0f + e1;
  const float r  = rcpf(d0 * d1);
  o0 = x0 * (r * d1);
  o1 = x1 * (r * d0);
}
__device__ __forceinline__ float softplusf(float x) {     // k_pre only (unchanged)
  return fmaxf(x, 0.0f) + log1pf(__expf(-fabsf(x)));
}
// in-loop softplus: z = e^-|x| in (0,1] -> 1+z in (1,2], v_log ~1ulp there.
__device__ __forceinline__ float softplus_fast(float x) {
  return fmaxf(x, 0.0f) + __logf(1.0f + __expf(-fabsf(x)));
}

__device__ __forceinline__ float bits_to_normal(uint32_t bits) {
  uint32_t fb = (bits >> 9) | 0x3F800000u;
  float f = __uint_as_float(fb) - 1.0f;
  float u = fmaf(f, 2.0f, -0.99999994f);
  u = fmaxf(u, -0.99999994f);
  float w = -log1pf(-u * u);
  float p;
  if (w < 5.0f) {
    w = w - 2.5f;
    p = 2.81022636e-08f;
    p = fmaf(p, w, 3.43273939e-07f);
    p = fmaf(p, w, -3.5233877e-06f);
    p = fmaf(p, w, -4.39150654e-06f);
    p = fmaf(p, w, 0.00021858087f);
    p = fmaf(p, w, -0.00125372503f);
    p = fmaf(p, w, -0.00417768164f);
    p = fmaf(p, w, 0.246640727f);
    p = fmaf(p, w, 1.50140941f);
  } else {
    w = sqrtf(w) - 3.0f;
    p = -0.000200214257f;
    p = fmaf(p, w, 0.000100950558f);
    p = fmaf(p, w, 0.00134934322f);
    p = fmaf(p, w, -0.00367342844f);
    p = fmaf(p, w, 0.00573950773f);
    p = fmaf(p, w, -0.0076224613f);
    p = fmaf(p, w, 0.00943887047f);
    p = fmaf(p, w, 1.00167406f);
    p = fmaf(p, w, 2.83297682f);
  }
  return 1.41421356237f * (p * u);
}

union FragHU { uint32_t u[4]; h16x8 v; };
union PkU    { fp16x2 h; uint32_t u; };

// split 8 fp32 -> 2 f16x8 fragments via v_cvt_pkrtz (1 op packs 2 values).
// x = hi + lo + eps, |eps| <= 2^-22|x| (f16 11-bit mantissa, 2 terms).
// ~24 VALU per 8 values vs split3's ~44, and 2 frags instead of 3.
__device__ __forceinline__ void split2h(const float (&x)[8], h16x8& fh, h16x8& fl) {
  FragHU Hh, Ll;
  #pragma unroll
  for (int d = 0; d < 4; ++d) {
    PkU hp; hp.h = __builtin_amdgcn_cvt_pkrtz(x[2*d], x[2*d+1]);
    const float r0 = x[2*d]     - (float)hp.h.x;
    const float r1 = x[2*d + 1] - (float)hp.h.y;
    PkU lp; lp.h = __builtin_amdgcn_cvt_pkrtz(r0, r1);
    Hh.u[d] = hp.u; Ll.u[d] = lp.u;
  }
  fh = Hh.v; fl = Ll.v;
}

#define MFMAH(A, B, C) __builtin_amdgcn_mfma_f32_16x16x32_f16((A), (B), (C), 0, 0, 0)

// ws layout (floats): [0,512) base_f1[b][j], [512,1024) base_g1[b][j],
// (u32 view) [1024,1152) keyA[t], [1152,1280) keyB[t]

__global__ void k_pre(const float* __restrict__ h_t,
                      const float* __restrict__ W_f1, const float* __restrict__ b_f1,
                      const float* __restrict__ W_g1, const float* __restrict__ b_g1,
                      const float* __restrict__ W_mu, const float* __restrict__ b_mu,
                      const float* __restrict__ W_sig, const float* __restrict__ b_sig,
                      float* __restrict__ out, float* __restrict__ ws) {
  int j = threadIdx.x;           // 0..63
  int b = blockIdx.x;
  if (b == 8) {
    uint32_t* keyA = (uint32_t*)ws + 1024;
    uint32_t* keyB = (uint32_t*)ws + 1152;
    for (int t = j; t < HOR; t += 64) {
      uint32_t x0 = 0u, x1 = (uint32_t)t;
      tf2x32(0u, 42u, x0, x1);
      keyA[t] = x0; keyB[t] = x1;
    }
    return;
  }
  const float* h = h_t + b * DM;
  float accF = b_f1[j], accG = b_g1[j];
  float pm = 0.0f, ps = 0.0f;
  #pragma unroll 4
  for (int d = 0; d < DM; ++d) {
    float hv = h[d];
    accF = fmaf(hv, W_f1[d * H + j], accF);
    accG = fmaf(hv, W_g1[d * H + j], accG);
  }
  ws[b * H + j] = accF;
  ws[512 + b * H + j] = accG;
  for (int d = j; d < DM; d += 64) {
    pm = fmaf(h[d], W_mu[d], pm);
    ps = fmaf(h[d], W_sig[d], ps);
  }
  #pragma unroll
  for (int off = 32; off > 0; off >>= 1) {
    pm += __shfl_down(pm, off);
    ps += __shfl_down(ps, off);
  }
  if (j == 0) {
    out[BN * HOR + b] = pm + b_mu[0];
    out[BN * HOR + 8 + b] = softplusf(ps + b_sig[0]) + 1e-6f;
  }
}

// -----------------------------------------------------------------------------
// R16 = R15 with the cvt_pkrtz type fixed (__fp16 vector return type; the
// MFMA operand h16x8 is filled via uint32 words so unaffected).
// R15 = R12 (419us, passed; 2 waves/SIMD — measured-best organization:
// {2wv TLP 419, 4wv split 570, 1wv ILP 453}) with ONE change: the emulated-
// fp32 matmul moves from bf16 3-split/6-product to F16 2-SPLIT/4-PRODUCT.
//   - f16 11-bit mantissa: 2-term split residual ~2^-22; 4 products
//     (hh,hl,lh,ll) -> ~2^-21 rel (was ~2^-23).
//   - split cost 88 -> ~48 VALU/lane-step via v_cvt_pkrtz (packs 2/op).
//   - MFMA 48 -> 32 (mfma_f32_16x16x32_f16, same rate + C/D layout).
//   - A-frags 96 -> 64 VGPRs (less pressure, more invariants resident).
//   VALUBusy ~82% at R11/R12 says VALU/issue-throughput is the wall; this is
//   the largest honest instruction cut left. All else identical to R12.
// -----------------------------------------------------------------------------
__global__ __launch_bounds__(256, 2)
void k_sde(const float* __restrict__ ip,
           const float* __restrict__ W_f1, const float* __restrict__ W_f2,
           const float* __restrict__ b_f2, const float* __restrict__ W_f3,
           const float* __restrict__ b_f3, const float* __restrict__ W_g1,
           const float* __restrict__ W_g2, const float* __restrict__ b_g2,
           float* __restrict__ out, const float* __restrict__ ws) {
  __shared__ __align__(16) float sW2[H * H];          // prologue staging only
  __shared__ __align__(16) float sF1y[H], sF1t[H], sBF[H];
  __shared__ __align__(16) float sGy[H], sGt[H], sBG[H], sG2[H];
  __shared__ __align__(16) float sF3[H], sBf2[H];
  __shared__ uint32_t sKA[HOR], sKB[HOR];

  const int tid  = threadIdx.x;
  const int rblk = blockIdx.x * 64;       // 64 rows per block (4 waves x 16)
  const int b    = rblk >> 12;            // batch: uniform per block

  #pragma unroll
  for (int m = 0; m < 16; ++m) sW2[tid + 256 * m] = W_f2[tid + 256 * m];
  if (tid < 64) {
    sF1y[tid] = W_f1[512 * H + tid];
    sF1t[tid] = W_f1[513 * H + tid];
    sGy[tid]  = W_g1[512 * H + tid];
    sGt[tid]  = W_g1[513 * H + tid];
    sF3[tid]  = W_f3[tid];
    sG2[tid]  = W_g2[tid];
    sBf2[tid] = b_f2[tid];
  } else if (tid < 128) {
    int i = tid - 64;
    sBF[i] = ws[b * H + i];
    sBG[i] = ws[512 + b * H + i];
  } else {
    const uint32_t* kws = (const uint32_t*)ws;
    int t = tid - 128;
    sKA[t] = kws[1024 + t];
    sKB[t] = kws[1152 + t];
  }
  __syncthreads();

  const int l  = tid & 63;
  const int wv = tid >> 6;
  const int rl = l & 15;                  // row-local / D column / B column
  const int h  = l >> 4;                  // k-group quarter
  const int r  = rblk + wv * 16 + rl;     // global row

  // ---- static A fragments: W2^T, f16 2-split (64 VGPRs) ----
  h16x8 aw[4][2][2];
  #pragma unroll
  for (int mt = 0; mt < 4; ++mt) {
    #pragma unroll
    for (int s = 0; s < 2; ++s) {
      float xv[8];
      #pragma unroll
      for (int e = 0; e < 8; ++e)
        xv[e] = sW2[(32 * s + 8 * h + e) * H + 16 * mt + rl];
      split2h(xv, aw[mt][s][0], aw[mt][s][1]);
    }
  }

  // per-lane f3 / b_f2 along D rows j = 16*mt + 4*h + reg
  f32x4 f3v[4], bf2v[4];
  #pragma unroll
  for (int mt = 0; mt < 4; ++mt) {
    f3v[mt]  = *(const f32x4*)&sF3[16 * mt + 4 * h];
    bf2v[mt] = *(const f32x4*)&sBf2[16 * mt + 4 * h];
  }

  // hoisted f1-row weights at this lane's k slots (48 VGPRs)
  f32x4 wy[2][2], wt1[2][2], wb[2][2];
  #pragma unroll
  for (int s = 0; s < 2; ++s) {
    const int k0 = 32 * s + 8 * h;
    wy[s][0]  = *(const f32x4*)&sF1y[k0]; wy[s][1]  = *(const f32x4*)&sF1y[k0 + 4];
    wt1[s][0] = *(const f32x4*)&sF1t[k0]; wt1[s][1] = *(const f32x4*)&sF1t[k0 + 4];
    wb[s][0]  = *(const f32x4*)&sBF[k0];  wb[s][1]  = *(const f32x4*)&sBF[k0 + 4];
  }

  const float bf3 = b_f3[0];
  const float bg2 = b_g2[0];
  float y  = logf(ip[b]);
  float zz = 0.0f;
  float sb0 = 0.f, sb1 = 0.f, sb2 = 0.f, sb3 = 0.f;   // 4-deep store shift reg

  #pragma unroll 1
  for (int t = 0; t < HOR; ++t) {
    // one threefry per lane per 4 steps: quarter h generates z for step t+h
    if ((t & 3) == 0) {
      const int tk = t + h;
      uint32_t x0 = 0u, x1 = (uint32_t)r;
      tf2x32(sKA[tk], sKB[tk], x0, x1);
      zz = bits_to_normal(x0 ^ x1);
    }
    const float z  = __shfl(zz, rl + 16 * (t & 3));
    const float tt = (float)t;

    // C init = b_f2[j] (folds the bias add into the accumulator)
    f32x4 c[4];
    #pragma unroll
    for (int mt = 0; mt < 4; ++mt) c[mt] = bf2v[mt];

    // ---- B fragments for both s phases (h1 = silu(pre), paired rcp) ----
    h16x8 bh[2], bl[2];
    #pragma unroll
    for (int s = 0; s < 2; ++s) {
      float pv[8], hv[8];
      #pragma unroll
      for (int d2 = 0; d2 < 2; ++d2) {
        const f32x4 a_ = wy[s][d2], b_ = wt1[s][d2], cc = wb[s][d2];
        pv[4*d2+0] = fmaf(y, a_.x, fmaf(tt, b_.x, cc.x));
        pv[4*d2+1] = fmaf(y, a_.y, fmaf(tt, b_.y, cc.y));
        pv[4*d2+2] = fmaf(y, a_.z, fmaf(tt, b_.z, cc.z));
        pv[4*d2+3] = fmaf(y, a_.w, fmaf(tt, b_.w, cc.w));
      }
      silu2(pv[0], pv[1], hv[0], hv[1]);
      silu2(pv[2], pv[3], hv[2], hv[3]);
      silu2(pv[4], pv[5], hv[4], hv[5]);
      silu2(pv[6], pv[7], hv[6], hv[7]);
      split2h(hv, bh[s], bl[s]);
    }

    // ---- 32 MFMAs, term-major: consecutive ops hit different accumulators ----
    #pragma unroll
    for (int s = 0; s < 2; ++s) {
      #pragma unroll
      for (int mt = 0; mt < 4; ++mt) c[mt] = MFMAH(aw[mt][s][0], bh[s], c[mt]); // hh
      #pragma unroll
      for (int mt = 0; mt < 4; ++mt) c[mt] = MFMAH(aw[mt][s][0], bl[s], c[mt]); // hl
      #pragma unroll
      for (int mt = 0; mt < 4; ++mt) c[mt] = MFMAH(aw[mt][s][1], bh[s], c[mt]); // lh
      #pragma unroll
      for (int mt = 0; mt < 4; ++mt) c[mt] = MFMAH(aw[mt][s][1], bl[s], c[mt]); // ll
    }

    // g-net from LDS (opaque index blocks LICM from hoisting 64 regs of loads);
    // independent of the MFMA chain -> schedules into its shadow.
    int kg = 8 * h;
    asm volatile("" : "+v"(kg));
    float ga0, ga1, ga2, ga3;
    {
      const int k0 = kg;
      const f32x4 gy0 = *(const f32x4*)&sGy[k0], gy1 = *(const f32x4*)&sGy[k0 + 4];
      const f32x4 gt0 = *(const f32x4*)&sGt[k0], gt1 = *(const f32x4*)&sGt[k0 + 4];
      const f32x4 gb0 = *(const f32x4*)&sBG[k0], gb1 = *(const f32x4*)&sBG[k0 + 4];
      const f32x4 g20 = *(const f32x4*)&sG2[k0], g21 = *(const f32x4*)&sG2[k0 + 4];
      float p0 = fmaf(y, gy0.x, fmaf(tt, gt0.x, gb0.x));
      float p1 = fmaf(y, gy0.y, fmaf(tt, gt0.y, gb0.y));
      float p2 = fmaf(y, gy0.z, fmaf(tt, gt0.z, gb0.z));
      float p3 = fmaf(y, gy0.w, fmaf(tt, gt0.w, gb0.w));
      float p4 = fmaf(y, gy1.x, fmaf(tt, gt1.x, gb1.x));
      float p5 = fmaf(y, gy1.y, fmaf(tt, gt1.y, gb1.y));
      float p6 = fmaf(y, gy1.z, fmaf(tt, gt1.z, gb1.z));
      float p7 = fmaf(y, gy1.w, fmaf(tt, gt1.w, gb1.w));
      float s0, s1, s2, s3, s4, s5, s6, s7;
      silu2(p0, p1, s0, s1); silu2(p2, p3, s2, s3);
      silu2(p4, p5, s4, s5); silu2(p6, p7, s6, s7);
      ga0 = s0 * g20.x;  ga1 = s1 * g20.y;
      ga2 = s2 * g20.z;  ga3 = s3 * g20.w;
      ga0 = fmaf(s4, g21.x, ga0); ga1 = fmaf(s5, g21.y, ga1);
      ga2 = fmaf(s6, g21.z, ga2); ga3 = fmaf(s7, g21.w, ga3);
    }
    {
      const int k0 = kg + 32;
      const f32x4 gy0 = *(const f32x4*)&sGy[k0], gy1 = *(const f32x4*)&sGy[k0 + 4];
      const f32x4 gt0 = *(const f32x4*)&sGt[k0], gt1 = *(const f32x4*)&sGt[k0 + 4];
      const f32x4 gb0 = *(const f32x4*)&sBG[k0], gb1 = *(const f32x4*)&sBG[k0 + 4];
      const f32x4 g20 = *(const f32x4*)&sG2[k0], g21 = *(const f32x4*)&sG2[k0 + 4];
      float p0 = fmaf(y, gy0.x, fmaf(tt, gt0.x, gb0.x));
      float p1 = fmaf(y, gy0.y, fmaf(tt, gt0.y, gb0.y));
      float p2 = fmaf(y, gy0.z, fmaf(tt, gt0.z, gb0.z));
      float p3 = fmaf(y, gy0.w, fmaf(tt, gt0.w, gb0.w));
      float p4 = fmaf(y, gy1.x, fmaf(tt, gt1.x, gb1.x));
      float p5 = fmaf(y, gy1.y, fmaf(tt, gt1.y, gb1.y));
      float p6 = fmaf(y, gy1.z, fmaf(tt, gt1.z, gb1.z));
      float p7 = fmaf(y, gy1.w, fmaf(tt, gt1.w, gb1.w));
      float s0, s1, s2, s3, s4, s5, s6, s7;
      silu2(p0, p1, s0, s1); silu2(p2, p3, s2, s3);
      silu2(p4, p5, s4, s5); silu2(p6, p7, s6, s7);
      ga0 = fmaf(s0, g20.x, ga0); ga1 = fmaf(s1, g20.y, ga1);
      ga2 = fmaf(s2, g20.z, ga2); ga3 = fmaf(s3, g20.w, ga3);
      ga0 = fmaf(s4, g21.x, ga0); ga1 = fmaf(s5, g21.y, ga1);
      ga2 = fmaf(s6, g21.z, ga2); ga3 = fmaf(s7, g21.w, ga3);
    }
    const float ga = (ga0 + ga1) + (ga2 + ga3);
    // ga butterfly: 3 parallel fetches (one DS round-trip, not two serial)
    const float gaA = __shfl_xor(ga, 16);
    const float gaB = __shfl_xor(ga, 32);
    const float gaC = __shfl_xor(ga, 48);

    // ---- f-head: paired-rcp silus, then 4 independent fma chains ----
    float s[16];
    silu2(c[0].x, c[0].y, s[0],  s[1]);  silu2(c[0].z, c[0].w, s[2],  s[3]);
    silu2(c[1].x, c[1].y, s[4],  s[5]);  silu2(c[1].z, c[1].w, s[6],  s[7]);
    silu2(c[2].x, c[2].y, s[8],  s[9]);  silu2(c[2].z, c[2].w, s[10], s[11]);
    silu2(c[3].x, c[3].y, s[12], s[13]); silu2(c[3].z, c[3].w, s[14], s[15]);
    float fa0 = s[0]  * f3v[0].x;
    float fa1 = s[4]  * f3v[1].x;
    float fa2 = s[8]  * f3v[2].x;
    float fa3 = s[12] * f3v[3].x;
    fa0 = fmaf(s[1],  f3v[0].y, fa0);
    fa1 = fmaf(s[5],  f3v[1].y, fa1);
    fa2 = fmaf(s[9],  f3v[2].y, fa2);
    fa3 = fmaf(s[13], f3v[3].y, fa3);
    fa0 = fmaf(s[2],  f3v[0].z, fa0);
    fa1 = fmaf(s[6],  f3v[1].z, fa1);
    fa2 = fmaf(s[10], f3v[2].z, fa2);
    fa3 = fmaf(s[14], f3v[3].z, fa3);
    fa0 = fmaf(s[3],  f3v[0].w, fa0);
    fa1 = fmaf(s[7],  f3v[1].w, fa1);
    fa2 = fmaf(s[11], f3v[2].w, fa2);
    fa3 = fmaf(s[15], f3v[3].w, fa3);
    const float fa = (fa0 + fa1) + (fa2 + fa3);
    // fa butterfly issued before ga is consumed (overlaps softplus below)
    const float faA = __shfl_xor(fa, 16);
    const float faB = __shfl_xor(fa, 32);
    const float faC = __shfl_xor(fa, 48);

    // consume ga (softplus runs under fa's DS latency)
    const float gaT = (ga + gaA) + (gaB + gaC);
    const float gg  = softplus_fast(bg2 + gaT) + 1e-6f;
    const float faT = (fa + faA) + (faB + faC);

    // Euler-Maruyama step
    y = (y + (bf3 + faT)) + gg * z;
    const float yl = fminf(fmaxf(y, -20.0f), 20.0f);
    const float e  = __expf(yl);
    // lane h owns t in [16m+4h, 16m+4h+3]; shift-register avoids dyn indexing
    if (((t >> 2) & 3) == h) { sb0 = sb1; sb1 = sb2; sb2 = sb3; sb3 = e; }
    if ((t & 15) == 15) {
      f32x4 v; v.x = sb0; v.y = sb1; v.z = sb2; v.w = sb3;
      *(f32x4*)&out[(size_t)r * HOR + (t & ~15) + 4 * h] = v;
    }
  }
}

extern "C" void kernel_launch(void* const* d_in, const int* in_sizes, int n_in,
                              void* d_out, int out_size, void* d_ws, size_t ws_size,
                              hipStream_t stream) {
  const float* h_t   = (const float*)d_in[0];
  const float* ip    = (const float*)d_in[1];
  const float* W_f1  = (const float*)d_in[2];
  const float* b_f1  = (const float*)d_in[3];
  const float* W_f2  = (const float*)d_in[4];
  const float* b_f2  = (const float*)d_in[5];
  const float* W_f3  = (const float*)d_in[6];
  const float* b_f3  = (const float*)d_in[7];
  const float* W_g1  = (const float*)d_in[8];
  const float* b_g1  = (const float*)d_in[9];
  const float* W_g2  = (const float*)d_in[10];
  const float* b_g2  = (const float*)d_in[11];
  const float* W_mu  = (const float*)d_in[12];
  const float* b_mu  = (const float*)d_in[13];
  const float* W_sig = (const float*)d_in[14];
  const float* b_sig = (const float*)d_in[15];
  float* out = (float*)d_out;
  float* ws  = (float*)d_ws;

  hipLaunchKernelGGL(k_pre, dim3(9), dim3(64), 0, stream,
                     h_t, W_f1, b_f1, W_g1, b_g1, W_mu, b_mu, W_sig, b_sig, out, ws);
  hipLaunchKernelGGL(k_sde, dim3(BN / 64), dim3(256), 0, stream,
                     ip, W_f1, W_f2, b_f2, W_f3, b_f3, W_g1, W_g2, b_g2, out, ws);
}